// Round 9
// baseline (17209.300 us; speedup 1.0000x reference)
//
#include <hip/hip_runtime.h>
#include <hip/hip_bf16.h>
#include <stdint.h>

#define B_ 128
#define T_ 256
#define S_ 256
#define I_ 512
#define H_ 512
#define CSLOT 4   // channel ring depth (WAR protected by dependency chain)

typedef __attribute__((ext_vector_type(8))) short short8;
typedef __attribute__((ext_vector_type(4))) float f32x4;
typedef unsigned short ushort_t;
typedef unsigned long long u64;
typedef unsigned int u32;

__device__ __forceinline__ float bf2f(ushort_t u){
  union{ u32 i; float f;} v; v.i = ((u32)u)<<16; return v.f;
}
__device__ __forceinline__ ushort_t f2bf(float f){
  union{ u32 i; float f;} v; v.f=f;
  u32 x=v.i; u32 r = x + 0x7fffu + ((x>>16)&1u);
  return (ushort_t)(r>>16);
}
__device__ __forceinline__ float sigm(float x){ return 1.f/(1.f + __expf(-x)); }
__device__ __forceinline__ float tanh_s(float x){
  float a = fabsf(x);
  float e = __expf(-2.f*a);
  float t = (1.f - e)/(1.f + e);
  return x < 0.f ? -t : t;
}

__device__ __forceinline__ f32x4 MFMA16(short8 a, short8 b, f32x4 c){
  typedef __attribute__((ext_vector_type(8))) __bf16 bf16x8;
  return __builtin_amdgcn_mfma_f32_16x16x32_bf16(
      __builtin_bit_cast(bf16x8, a), __builtin_bit_cast(bf16x8, b), c, 0, 0, 0);
}

// agent-scope 8B atomic store/load: the coherence primitive for all channels
__device__ __forceinline__ void ch_st(u64* p, u32 tag, u32 payload){
  __hip_atomic_store(p, ((u64)tag << 32) | payload,
                     __ATOMIC_RELAXED, __HIP_MEMORY_SCOPE_AGENT);
}
__device__ __forceinline__ u64 ch_ld(const u64* p){
  return __hip_atomic_load(p, __ATOMIC_RELAXED, __HIP_MEMORY_SCOPE_AGENT);
}
// poll one word until its embedded tag matches; tag+payload are one atom
__device__ __forceinline__ u32 ch_poll(const u64* p, u32 tag){
  u64 w = ch_ld(p);
  while ((u32)(w >> 32) != tag){
    __builtin_amdgcn_s_sleep(1);
    w = ch_ld(p);
  }
  return (u32)w;
}

// ---------------- converts / init ----------------

__global__ void k_cvt_bf16(const float* __restrict__ src, ushort_t* __restrict__ dst, int n){
  int i = (blockIdx.x*blockDim.x + threadIdx.x)*4;
  int stride = gridDim.x*blockDim.x*4;
  for (; i < n; i += stride){
    float4 v = *(const float4*)(src + i);
    ushort4 o; o.x=f2bf(v.x); o.y=f2bf(v.y); o.z=f2bf(v.z); o.w=f2bf(v.w);
    *(ushort4*)(dst + i) = o;
  }
}

// reset ALL channel words to tag 0 (no poll tag is ever 0) — replay safety
__global__ void k_zero_ch(u64* p, int n){
  int i = blockIdx.x*blockDim.x + threadIdx.x;
  if (i < n)
    __hip_atomic_store(p + i, 0ull, __ATOMIC_RELAXED, __HIP_MEMORY_SCOPE_AGENT);
}

// h0 -> hCh slot 0 with tag 1; c0 -> cyb
__global__ void k_init_state(const float* __restrict__ h0, const float* __restrict__ c0,
                             u64* __restrict__ hCh, float* __restrict__ cyb){
  int i = blockIdx.x*256 + threadIdx.x; // 65536
  cyb[i] = c0[i];
  if (i < 32768){
    int b = i >> 8, w = i & 255;
    u32 p = (u32)f2bf(h0[b*512 + w*2]) | ((u32)f2bf(h0[b*512 + w*2 + 1]) << 16);
    __hip_atomic_store(hCh + i, ((u64)1 << 32) | p,
                       __ATOMIC_RELAXED, __HIP_MEMORY_SCOPE_AGENT);
  }
}

// ---------------- precompute GEMM (Xg, gate-interleaved output) ----------------
// Xg2[((b*T+t)*512 + h)*4 + gate] = (x @ Wi^T + bi + bh)
__global__ __launch_bounds__(256) void k_gemm_bt(
    const float* __restrict__ A, const float* __restrict__ Bm,
    ushort_t* __restrict__ C, int M, int N, int K,
    const float* __restrict__ bias0, const float* __restrict__ bias1){
  __shared__ ushort_t Asm[128][40];
  __shared__ ushort_t Bsm[128][40];
  const int tid = threadIdx.x;
  const int mBase = blockIdx.x*128, nBase = blockIdx.y*128;
  const int l = tid & 63, wv = tid >> 6;
  const int wm = (wv>>1)*64, wn = (wv&1)*64;
  const int lr = l & 15, lq = l >> 4;
  const int srow = tid >> 1, scol = (tid & 1)*16;
  const float* Ap = A + (size_t)(mBase + srow)*K + scol;
  const float* Bp = Bm + (size_t)(nBase + srow)*K + scol;

  f32x4 acc[4][4];
  #pragma unroll
  for (int i=0;i<4;i++)
    #pragma unroll
    for (int j=0;j<4;j++) acc[i][j] = (f32x4)0.f;

  for (int k0 = 0; k0 < K; k0 += 32){
    float4 a0 = *(const float4*)(Ap + k0);
    float4 a1 = *(const float4*)(Ap + k0 + 4);
    float4 a2 = *(const float4*)(Ap + k0 + 8);
    float4 a3 = *(const float4*)(Ap + k0 + 12);
    float4 b0 = *(const float4*)(Bp + k0);
    float4 b1 = *(const float4*)(Bp + k0 + 4);
    float4 b2 = *(const float4*)(Bp + k0 + 8);
    float4 b3 = *(const float4*)(Bp + k0 + 12);
    __syncthreads();
    {
      ushort4 w;
      w.x=f2bf(a0.x); w.y=f2bf(a0.y); w.z=f2bf(a0.z); w.w=f2bf(a0.w);
      *(ushort4*)&Asm[srow][scol+0]  = w;
      w.x=f2bf(a1.x); w.y=f2bf(a1.y); w.z=f2bf(a1.z); w.w=f2bf(a1.w);
      *(ushort4*)&Asm[srow][scol+4]  = w;
      w.x=f2bf(a2.x); w.y=f2bf(a2.y); w.z=f2bf(a2.z); w.w=f2bf(a2.w);
      *(ushort4*)&Asm[srow][scol+8]  = w;
      w.x=f2bf(a3.x); w.y=f2bf(a3.y); w.z=f2bf(a3.z); w.w=f2bf(a3.w);
      *(ushort4*)&Asm[srow][scol+12] = w;
      w.x=f2bf(b0.x); w.y=f2bf(b0.y); w.z=f2bf(b0.z); w.w=f2bf(b0.w);
      *(ushort4*)&Bsm[srow][scol+0]  = w;
      w.x=f2bf(b1.x); w.y=f2bf(b1.y); w.z=f2bf(b1.z); w.w=f2bf(b1.w);
      *(ushort4*)&Bsm[srow][scol+4]  = w;
      w.x=f2bf(b2.x); w.y=f2bf(b2.y); w.z=f2bf(b2.z); w.w=f2bf(b2.w);
      *(ushort4*)&Bsm[srow][scol+8]  = w;
      w.x=f2bf(b3.x); w.y=f2bf(b3.y); w.z=f2bf(b3.z); w.w=f2bf(b3.w);
      *(ushort4*)&Bsm[srow][scol+12] = w;
    }
    __syncthreads();
    short8 aF[4], bF[4];
    #pragma unroll
    for (int i=0;i<4;i++) aF[i] = *(const short8*)&Asm[wm + i*16 + lr][lq*8];
    #pragma unroll
    for (int j=0;j<4;j++) bF[j] = *(const short8*)&Bsm[wn + j*16 + lr][lq*8];
    #pragma unroll
    for (int i=0;i<4;i++)
      #pragma unroll
      for (int j=0;j<4;j++)
        acc[i][j] = MFMA16(aF[i], bF[j], acc[i][j]);
  }

  #pragma unroll
  for (int j=0;j<4;j++){
    int col = nBase + wn + j*16 + lr;
    float bsum = bias0[col] + bias1[col];
    int h = col & 511, gatec = col >> 9;
    #pragma unroll
    for (int i=0;i<4;i++){
      int row0 = mBase + wm + i*16 + lq*4;
      #pragma unroll
      for (int r=0;r<4;r++)
        C[((size_t)(row0+r)*512 + h)*4 + gatec] = f2bf(acc[i][j][r] + bsum);
    }
  }
}

// ---------------- persistent recurrence kernel — BARRIER-FREE ----------------
// 256 blocks x 512 threads, 1 block/CU. All cross-block state moves as tagged
// 64-bit atomic words: (step_tag<<32)|payload. Readers poll the word itself —
// tag+payload are one atom, so visibility is exact regardless of timing.
// Channel word layout (u64):
//   hyCh/hCh/wcCh: ((slot*128 + b)*256 + widx), widx=col/2
//   psCh: (((slot*128 + bB)*2 + half)*256 + s)   (f32 payload)

__global__ __launch_bounds__(512) void k_persist(
    const ushort_t* __restrict__ Xg2, const float* __restrict__ ctx,
    const ushort_t* __restrict__ Whb, const ushort_t* __restrict__ Woutb,
    const ushort_t* __restrict__ Winb,
    u64* hCh, u64* hyCh, u64* wcCh, u64* psCh,
    float* cyb, float* out, float* hf, float* cf)
{
  extern __shared__ __align__(16) char ctx_s[];   // 131072 B: [256 s][256 h-half] bf16, swizzled

  __shared__ __align__(16) union {
    struct { float red[8][256]; ushort_t pk[256]; char hstage[16384]; } a;
    struct { float hy[512]; float tg[256]; float ps[256]; float sc[256];
             float p[256]; float inv; float pad;
             float pacc[16][256]; ushort_t pk[256]; } b;
  } sh;

  const int pbid = blockIdx.x;
  const int tid = threadIdx.x;
  const int l = tid & 63, wv = tid >> 6;     // 8 waves
  const int lr = l & 15, lq = l >> 4;

  // ---- pin weight fragments in registers ----
  const int bm = pbid >> 5, hc = pbid & 31;       // phase A / C tiles
  const int gate = wv & 3, khalf = wv >> 2;
  short8 whr[8];
  #pragma unroll
  for (int kk=0;kk<8;kk++)
    whr[kk] = *(const short8*)(Whb + (size_t)(gate*512 + hc*16 + lr)*512
                               + khalf*256 + lq*8 + kk*32);
  short8 wor[4];
  #pragma unroll
  for (int kk=0;kk<4;kk++)
    wor[kk] = *(const short8*)(Woutb + (size_t)(hc*16 + lr)*1024
                               + wv*128 + lq*8 + kk*32);

  const int bB = pbid >> 1, half = pbid & 1;      // phase B ids
  const int bA = bm*16 + ((tid & 255) >> 4), hA = hc*16 + (tid & 15);  // A/C elem

  // ---- one-time: stage this block's ctx half into LDS (swizzled) ----
  {
    const float* cp = ctx + (size_t)bB*512 + half*256 + (tid & 63)*4;
    #pragma unroll 4
    for (int i = 0; i < 32; ++i){
      int s = i*8 + (tid >> 6);
      float4 v = *(const float4*)(cp + (size_t)s*65536);
      ushort4 o; o.x=f2bf(v.x); o.y=f2bf(v.y); o.z=f2bf(v.z); o.w=f2bf(v.w);
      int boff = ((tid & 63)*8) ^ ((s & 7) << 4);
      *(ushort4*)(ctx_s + s*512 + boff) = o;
    }
  }
  __syncthreads();

  ushort4 xq_cur = make_ushort4(0,0,0,0), xq_next = make_ushort4(0,0,0,0);
  if (tid < 256)
    xq_cur = *(const ushort4*)(Xg2 + ((size_t)(bA*T_ + 0)*512 + hA)*4);

  for (int t = 0; t < T_; ++t){
    const int slot = t & (CSLOT-1);
    const u32 tg1 = (u32)(t + 1);   // tag for everything produced/consumed at step t

    // ======== Phase A: gates = Xg[:,t,:] + h @ Wh^T ; LSTM pointwise ========
    {
      float co = 0.f;
      if (tid < 256) co = cyb[bA*512 + hA];
      // cooperative tagged load of h(t) tile (16 rows x 256 words) -> LDS
      {
        const int r = tid >> 5, w8 = (tid & 31)*8;
        const u64* hp = hCh + ((size_t)(slot*128 + bm*16 + r)*256) + w8;
        u64 hw[8];
        #pragma unroll
        for (int j=0;j<8;j++) hw[j] = ch_ld(hp + j);
        #pragma unroll
        for (int j=0;j<8;j++){
          while ((u32)(hw[j] >> 32) != tg1){
            __builtin_amdgcn_s_sleep(1);
            hw[j] = ch_ld(hp + j);
          }
        }
        #pragma unroll
        for (int j=0;j<8;j++)
          *(u32*)(sh.a.hstage + r*1024 + ((((w8 + j)*4)) ^ ((r & 7) << 6))) = (u32)hw[j];
      }
      __syncthreads();
      f32x4 acc = (f32x4)0.f;
      #pragma unroll
      for (int kk=0;kk<8;kk++){
        int u = khalf*512 + kk*64 + lq*16;
        short8 aF = *(const short8*)(sh.a.hstage + lr*1024 + (u ^ ((lr & 7) << 6)));
        acc = MFMA16(aF, whr[kk], acc);
      }
      #pragma unroll
      for (int r=0;r<4;r++) sh.a.red[wv][(lq*4+r)*16+lr] = acc[r];
      __syncthreads();
      if (tid < 256){
        float gi  = sh.a.red[0][tid] + sh.a.red[4][tid] + bf2f(xq_cur.x);
        float gf  = sh.a.red[1][tid] + sh.a.red[5][tid] + bf2f(xq_cur.y);
        float gg  = sh.a.red[2][tid] + sh.a.red[6][tid] + bf2f(xq_cur.z);
        float go_ = sh.a.red[3][tid] + sh.a.red[7][tid] + bf2f(xq_cur.w);
        float cn = sigm(gf)*co + sigm(gi)*tanh_s(gg);
        float hn = sigm(go_)*tanh_s(cn);
        cyb[bA*512 + hA] = cn;
        sh.a.pk[tid] = f2bf(hn);
        if (t == T_-1) cf[bA*512 + hA] = cn;
      }
      __syncthreads();
      if (tid < 128){
        int r = tid >> 3, wi = tid & 7;
        u32 p = (u32)sh.a.pk[r*16 + wi*2] | ((u32)sh.a.pk[r*16 + wi*2 + 1] << 16);
        ch_st(hyCh + ((size_t)(slot*128 + bm*16 + r)*256) + hc*8 + wi, tg1, p);
      }
    }

    // ======== Phase B1: target GEMV + partial scores -> tagged mailbox ========
    {
      // prefetch next step's Xg slice
      if (tid < 256){
        int tn = (t+1 < T_) ? t+1 : t;
        xq_next = *(const ushort4*)(Xg2 + ((size_t)(bA*T_ + tn)*512 + hA)*4);
      }
      // hy[bB] via tagged poll -> LDS (f32)
      if (tid < 256){
        u32 p = ch_poll(hyCh + ((size_t)(slot*128 + bB)*256) + tid, tg1);
        sh.b.hy[tid*2]   = bf2f((ushort_t)(p & 0xffffu));
        sh.b.hy[tid*2+1] = bf2f((ushort_t)(p >> 16));
      }
      __syncthreads();
      // target_half[j] = sum_k hy[k]*Win[half*256+j][k]  (Win L2-resident)
      {
        const int j = tid >> 1, kh = tid & 1;
        const ushort_t* wp = Winb + (size_t)(half*256 + j)*512 + kh*256;
        float d = 0.f;
        #pragma unroll
        for (int c = 0; c < 32; ++c){
          short8 w8 = *(const short8*)(wp + c*8);
          #pragma unroll
          for (int e=0;e<8;e++) d += bf2f((ushort_t)w8[e]) * sh.b.hy[kh*256 + c*8 + e];
        }
        d += __shfl_xor(d, 1);
        if (kh == 0) sh.b.tg[j] = d;
      }
      __syncthreads();
      // partial scores over this h-half: ps[s] = sum_j tg[j]*ctx_s[s][j]
      {
        const int s = tid >> 1, qh = tid & 1;
        const int swz = (s & 7) << 4;
        float d = 0.f;
        #pragma unroll
        for (int c = 0; c < 16; ++c){
          int eb = c*16 + qh*8;
          short8 cv = *(const short8*)(ctx_s + s*512 + ((eb*2) ^ swz));
          #pragma unroll
          for (int e=0;e<8;e++) d += bf2f((ushort_t)cv[e]) * sh.b.tg[eb + e];
        }
        d += __shfl_xor(d, 1);
        if (qh == 0) sh.b.ps[s] = d;
      }
      __syncthreads();
      if (tid < 256)
        ch_st(psCh + (((size_t)(slot*128 + bB)*2 + half)*256) + tid,
              tg1, __builtin_bit_cast(u32, sh.b.ps[tid]));
    }

    // ======== Phase B2: combine scores (tagged poll), softmax, wc ========
    {
      if (tid < 256){
        u32 p = ch_poll(psCh + (((size_t)(slot*128 + bB)*2 + (half^1))*256) + tid, tg1);
        sh.b.sc[tid] = sh.b.ps[tid] + __builtin_bit_cast(float, p);
      }
      __syncthreads();
      if (wv == 0){
        float v0=sh.b.sc[l], v1=sh.b.sc[l+64], v2=sh.b.sc[l+128], v3=sh.b.sc[l+192];
        float m = fmaxf(fmaxf(v0,v1), fmaxf(v2,v3));
        #pragma unroll
        for (int off=32; off; off>>=1) m = fmaxf(m, __shfl_xor(m, off));
        float e0=__expf(v0-m), e1=__expf(v1-m), e2=__expf(v2-m), e3=__expf(v3-m);
        float s4 = (e0+e1)+(e2+e3);
        #pragma unroll
        for (int off=32; off; off>>=1) s4 += __shfl_xor(s4, off);
        sh.b.p[l]=e0; sh.b.p[l+64]=e1; sh.b.p[l+128]=e2; sh.b.p[l+192]=e3;
        if (l==0) sh.b.inv = 1.f/s4;
      }
      __syncthreads();
      {
        const int g = tid & 31, p2 = tid >> 5;
        float a8[8];
        #pragma unroll
        for (int e=0;e<8;e++) a8[e]=0.f;
        #pragma unroll
        for (int j=0;j<16;j++){
          int s = p2*16 + j;
          short8 cv = *(const short8*)(ctx_s + s*512 + ((g*16) ^ ((s&7)<<4)));
          float pw = sh.b.p[s];
          #pragma unroll
          for (int e=0;e<8;e++) a8[e] += pw * bf2f((ushort_t)cv[e]);
        }
        #pragma unroll
        for (int e=0;e<8;e++) sh.b.pacc[p2][g*8+e] = a8[e];
      }
      __syncthreads();
      if (tid < 256){
        float ssum = 0.f;
        #pragma unroll
        for (int p2=0;p2<16;p2++) ssum += sh.b.pacc[p2][tid];
        sh.b.pk[tid] = f2bf(ssum * sh.b.inv);
      }
      __syncthreads();
      if (tid < 128)
        ch_st(wcCh + ((size_t)(slot*128 + bB)*256) + half*128 + tid,
              tg1, (u32)sh.b.pk[tid*2] | ((u32)sh.b.pk[tid*2+1] << 16));
    }

    // ======== Phase C: h_tilde = tanh([wc|hy] @ W_out^T) ========
    {
      const u64* chb = (wv < 4) ? wcCh : hyCh;
      const u64* cp0 = chb + ((size_t)(slot*128 + bm*16 + lr)*256) + (wv&3)*64 + lq*4;
      u64 w[16];
      #pragma unroll
      for (int kk=0;kk<4;kk++)
        #pragma unroll
        for (int j=0;j<4;j++) w[kk*4+j] = ch_ld(cp0 + kk*16 + j);
      #pragma unroll
      for (int i=0;i<16;i++){
        while ((u32)(w[i] >> 32) != tg1){
          __builtin_amdgcn_s_sleep(1);
          w[i] = ch_ld(cp0 + (i>>2)*16 + (i&3));
        }
      }
      f32x4 acc = (f32x4)0.f;
      #pragma unroll
      for (int kk=0;kk<4;kk++){
        int4 q;
        q.x = (int)(u32)w[kk*4+0]; q.y = (int)(u32)w[kk*4+1];
        q.z = (int)(u32)w[kk*4+2]; q.w = (int)(u32)w[kk*4+3];
        acc = MFMA16(__builtin_bit_cast(short8, q), wor[kk], acc);
      }
      #pragma unroll
      for (int r=0;r<4;r++) sh.a.red[wv][(lq*4+r)*16+lr] = acc[r];
      __syncthreads();
      if (tid < 256){
        float s = 0.f;
        #pragma unroll
        for (int w8=0;w8<8;w8++) s += sh.a.red[w8][tid];
        float v = tanh_s(s);
        out[((size_t)bA*T_ + t)*512 + hA] = v;
        sh.a.pk[tid] = f2bf(v);
        if (t == T_-1) hf[bA*512 + hA] = v;
      }
      __syncthreads();
      if (tid < 128){
        int r = tid >> 3, wi = tid & 7;
        u32 p = (u32)sh.a.pk[r*16 + wi*2] | ((u32)sh.a.pk[r*16 + wi*2 + 1] << 16);
        ch_st(hCh + ((size_t)(((t+1) & (CSLOT-1))*128 + bm*16 + r)*256) + hc*8 + wi,
              (u32)(t + 2), p);
      }
    }
    xq_cur = xq_next;
  }
}

// ---------------- host ----------------

extern "C" void kernel_launch(void* const* d_in, const int* in_sizes, int n_in,
                              void* d_out, int out_size, void* d_ws, size_t ws_size,
                              hipStream_t stream){
  const float* x    = (const float*)d_in[0];
  const float* h0   = (const float*)d_in[1];
  const float* c0   = (const float*)d_in[2];
  const float* ctx  = (const float*)d_in[3];
  const float* Wi   = (const float*)d_in[4];
  const float* bi   = (const float*)d_in[5];
  const float* Wh   = (const float*)d_in[6];
  const float* bh   = (const float*)d_in[7];
  const float* Win  = (const float*)d_in[8];
  const float* Wout = (const float*)d_in[9];

  char* ws = (char*)d_ws;
  ushort_t* Xg2   = (ushort_t*)(ws);                 // 134217728
  ushort_t* Whb   = (ushort_t*)(ws + 134217728);     //   2097152
  ushort_t* Woutb = (ushort_t*)(ws + 136314880);     //   1048576
  ushort_t* Winb  = (ushort_t*)(ws + 137363456);     //    524288
  u64*      hyCh  = (u64*)     (ws + 137887744);     //   1048576 (4 slots)
  u64*      hCh   = (u64*)     (ws + 138936320);     //   1048576
  u64*      wcCh  = (u64*)     (ws + 139984896);     //   1048576
  u64*      psCh  = (u64*)     (ws + 141033472);     //   2097152
  float*    cyb   = (float*)   (ws + 143130624);     //    262144

  float* out = (float*)d_out;
  float* hf  = out + (size_t)B_*T_*H_;
  float* cf  = hf + (size_t)B_*H_;

  // allow 128 KB dynamic LDS (static ~25 KB + 128 KB < 160 KB/CU)
  hipFuncSetAttribute((const void*)k_persist,
                      hipFuncAttributeMaxDynamicSharedMemorySize, 131072);

  // reset all channel tags (replay safety), then init h0/c0
  k_zero_ch<<<2560, 256, 0, stream>>>(hyCh, 655360);  // hy+h+wc+ps contiguous
  k_init_state<<<256, 256, 0, stream>>>(h0, c0, hCh, cyb);

  // converts
  k_cvt_bf16<<<512, 256, 0, stream>>>(Wh, Whb, 4*H_*H_);
  k_cvt_bf16<<<512, 256, 0, stream>>>(Wout, Woutb, H_*2*H_);
  k_cvt_bf16<<<256, 256, 0, stream>>>(Win, Winb, H_*H_);

  // Xg2 = x @ Wi^T + (bi + bh), gate-interleaved [b][t][h][4]
  k_gemm_bt<<<dim3(256,16), 256, 0, stream>>>(x, Wi, Xg2, B_*T_, 4*H_, I_, bi, bh);

  // whole recurrence; barrier-free tagged-channel dataflow
  k_persist<<<256, 512, 131072, stream>>>(Xg2, ctx, Whb, Woutb, Winb,
                                          hCh, hyCh, wcCh, psCh,
                                          cyb, out, hf, cf);
}